// Round 5
// baseline (309.022 us; speedup 1.0000x reference)
//
#include <hip/hip_runtime.h>
#include <hip/hip_bf16.h>
#include <math.h>

#define Dm 1024
#define Tm 2048
#define Bm 2
#define Hm 16
#define HDm 64
#define Rm (Bm*Tm)   // 4096 rows
#define QKS 2048     // q|k row stride (dense, V split out)

typedef __attribute__((ext_vector_type(8))) short sh8;    // 8 bf16 (4 VGPRs)
typedef __attribute__((ext_vector_type(4))) float f32x4;  // MFMA C/D frag

#define AS1(p) ((const __attribute__((address_space(1))) void*)(p))
#define AS3(p) ((__attribute__((address_space(3))) void*)(p))

// fp32 -> bf16 bits, round-to-nearest-even
__device__ __forceinline__ short f2bs(float f) {
    union { float f; unsigned u; } v; v.f = f;
    unsigned r = v.u + 0x7FFFu + ((v.u >> 16) & 1u);
    return (short)(r >> 16);
}

// ---------------- weight convert: wq,wk,wv -> wqkv (bf16), wo -> wob ----
// wq is pre-scaled by 0.125 (1/sqrt(64)) so attention skips the scale.
// Exact: power-of-2 scaling commutes with bf16 rounding and fp32 accum.
__global__ __launch_bounds__(256) void convert_w(const float* __restrict__ wq,
                                                 const float* __restrict__ wk,
                                                 const float* __restrict__ wv,
                                                 const float* __restrict__ wo,
                                                 short* __restrict__ wqkv,
                                                 short* __restrict__ wob) {
    int idx = (blockIdx.x * 256 + threadIdx.x) * 4;   // 4 elems/thread, 4M total
    const int M1 = 1 << 20;
    const float* src; short* dst; int off; float sc = 1.0f;
    if (idx < M1)           { src = wq; dst = wqkv;          off = idx; sc = 0.125f; }
    else if (idx < 2*M1)    { src = wk; dst = wqkv + M1;     off = idx - M1; }
    else if (idx < 3*M1)    { src = wv; dst = wqkv + 2*M1;   off = idx - 2*M1; }
    else                    { src = wo; dst = wob;           off = idx - 3*M1; }
    float4 v = *(const float4*)(src + off);
    short4 o;
    o.x = f2bs(v.x*sc); o.y = f2bs(v.y*sc); o.z = f2bs(v.z*sc); o.w = f2bs(v.w*sc);
    *(short4*)(dst + off) = o;
}

// ---------------- LayerNorm: one block (256 thr) per row, bf16 out ------
__global__ __launch_bounds__(256) void ln_kernel(const float* __restrict__ x,
                                                 const float* __restrict__ scale,
                                                 short* __restrict__ out) {
    int row = blockIdx.x;
    int t = threadIdx.x;
    const float4* xr = (const float4*)(x + (size_t)row * Dm);
    float4 v = xr[t];
    float s  = v.x + v.y + v.z + v.w;
    float ss = v.x*v.x + v.y*v.y + v.z*v.z + v.w*v.w;
    #pragma unroll
    for (int off = 32; off; off >>= 1) {
        s  += __shfl_xor(s, off);
        ss += __shfl_xor(ss, off);
    }
    __shared__ float red[8];
    int wave = t >> 6, lane = t & 63;
    if (lane == 0) { red[wave*2] = s; red[wave*2+1] = ss; }
    __syncthreads();
    s  = red[0] + red[2] + red[4] + red[6];
    ss = red[1] + red[3] + red[5] + red[7];
    float mean = s * (1.0f / Dm);
    float var  = ss * (1.0f / Dm) - mean * mean;
    float rstd = 1.0f / sqrtf(var + 1e-5f);
    float4 sc = ((const float4*)scale)[t];
    short4 o;
    o.x = f2bs(sc.x * ((v.x - mean) * rstd) + sc.x);
    o.y = f2bs(sc.y * ((v.y - mean) * rstd) + sc.y);
    o.z = f2bs(sc.z * ((v.z - mean) * rstd) + sc.z);
    o.w = f2bs(sc.w * ((v.w - mean) * rstd) + sc.w);
    ((short4*)(out + (size_t)row * Dm))[t] = o;
}

// ---------------- MFMA GEMM (m97 structure): C = A @ B^T ----------------
// MODE 0: float out + bias + residual (proj GEMM)
// MODE 1: QKV gemm: n<2048 -> bf16 into qk buffer (stride 2048);
//         n>=2048 -> V part stored TRANSPOSED per head: vtg[b][h][d][key]
template<int BN, int MODE>
__global__ __launch_bounds__(256) void gemm_mfma(const short* __restrict__ A,
                                                 const short* __restrict__ B,
                                                 const float* __restrict__ bias,
                                                 const float* __restrict__ res,
                                                 void* __restrict__ Cv,
                                                 short* __restrict__ Vt,
                                                 int M, int N, int K) {
    __shared__ short As[128*32];
    __shared__ short Bs[BN*32];
    __shared__ short Tb[(MODE==1) ? 4*16*68 : 4];   // per-wave transpose bounce
    const int NJ = BN / 32;            // 16x16 j-tiles per wave
    int t = threadIdx.x;
    int lane = t & 63, w = t >> 6;
    int l = lane & 15, quad = lane >> 4;
    int wm = (w & 1) * 64, wn = (w >> 1) * (BN/2);
    int m0 = blockIdx.y * 128, n0 = blockIdx.x * BN;

    f32x4 acc[4][NJ];
    #pragma unroll
    for (int i = 0; i < 4; i++)
        #pragma unroll
        for (int j = 0; j < NJ; j++)
            acc[i][j] = (f32x4){0.f,0.f,0.f,0.f};

    for (int k0 = 0; k0 < K; k0 += 32) {
        __syncthreads();
        #pragma unroll
        for (int p = 0; p < 2; p++) {            // A tile: 128 rows
            int off = p*4096 + t*16;             // LDS byte offset
            int row = off >> 6;
            int c = ((off >> 4) & 3) ^ (row & 3);
            const short* ga = A + (size_t)(m0 + row) * K + k0 + c*8;
            __builtin_amdgcn_global_load_lds(AS1(ga), AS3((char*)As + off), 16, 0, 0);
        }
        #pragma unroll
        for (int p = 0; p < BN/64; p++) {        // B tile: BN rows
            int off = p*4096 + t*16;
            int row = off >> 6;
            int c = ((off >> 4) & 3) ^ (row & 3);
            const short* gb = B + (size_t)(n0 + row) * K + k0 + c*8;
            __builtin_amdgcn_global_load_lds(AS1(gb), AS3((char*)Bs + off), 16, 0, 0);
        }
        __syncthreads();
        sh8 af[4], bf[NJ];
        #pragma unroll
        for (int i = 0; i < 4; i++) {
            int m = wm + i*16 + l;
            af[i] = *(const sh8*)((const char*)As + m*64 + ((quad ^ (m & 3)) * 16));
        }
        #pragma unroll
        for (int j = 0; j < NJ; j++) {
            int n = wn + j*16 + l;
            bf[j] = *(const sh8*)((const char*)Bs + n*64 + ((quad ^ (n & 3)) * 16));
        }
        #pragma unroll
        for (int i = 0; i < 4; i++)
            #pragma unroll
            for (int j = 0; j < NJ; j++)
                acc[i][j] = __builtin_amdgcn_mfma_f32_16x16x32_bf16(af[i], bf[j], acc[i][j], 0, 0, 0);
    }
    // epilogue
    if (MODE == 0) {
        #pragma unroll
        for (int i = 0; i < 4; i++)
            #pragma unroll
            for (int j = 0; j < NJ; j++)
                #pragma unroll
                for (int r = 0; r < 4; r++) {
                    int m = m0 + wm + i*16 + quad*4 + r;
                    int n = n0 + wn + j*16 + l;
                    float vv = acc[i][j][r] + bias[n] + res[(size_t)m * N + n];
                    ((float*)Cv)[(size_t)m * N + n] = vv;
                }
    } else {
        if (n0 < 2048) {
            // q,k part: bf16 store at dense stride 2048
            #pragma unroll
            for (int i = 0; i < 4; i++)
                #pragma unroll
                for (int j = 0; j < NJ; j++)
                    #pragma unroll
                    for (int r = 0; r < 4; r++) {
                        int m = m0 + wm + i*16 + quad*4 + r;
                        int n = n0 + wn + j*16 + l;
                        ((short*)Cv)[(size_t)m * QKS + n] = f2bs(acc[i][j][r]);
                    }
        } else {
            // V part: transpose via per-wave LDS bounce -> vtg[bh][d][key]
            int bq = m0 >> 11;                    // batch
            int key0 = (m0 & 2047) + wm;          // wave's key base
            int h = (n0 + wn - 2048) >> 6;        // wave covers exactly one head
            short* vout = Vt + ((size_t)(bq*Hm + h) * HDm) * Tm + key0;
            #pragma unroll
            for (int j = 0; j < NJ; j++) {
                #pragma unroll
                for (int i = 0; i < 4; i++) {
                    short4 o;
                    o.x = f2bs(acc[i][j][0]); o.y = f2bs(acc[i][j][1]);
                    o.z = f2bs(acc[i][j][2]); o.w = f2bs(acc[i][j][3]);
                    *(short4*)&Tb[w*(16*68) + l*68 + i*16 + quad*4] = o;
                }
                #pragma unroll
                for (int st = 0; st < 2; st++) {
                    int rr = st*8 + (lane >> 3);
                    int cc = lane & 7;
                    sh8 vv = *(const sh8*)&Tb[w*(16*68) + rr*68 + cc*8];
                    *(sh8*)(vout + (size_t)(j*16 + rr) * Tm + cc*8) = vv;
                }
            }
        }
    }
}

// ---------------- MFMA flash attention, S^T form, no online max ---------
// v5: split-K. Grid (bh=32, y=48). y<16: qt=y, full key range, direct
// normalized bf16 output. y>=16: qt=16+((y-16)>>1), half=(y-16)&1 ->
// key-range half, writes UN-normalized fp32 partial O + psum (additive
// since p=exp(s) raw, no online max). attn_combine sums+normalizes.
// Critical path: 32 -> 16 chunks. x=bh keeps per-bh K/V in one XCD L2.
// All staging addresses hoisted out of the kc loop (constant increments).
__global__ __launch_bounds__(256) void attn_mfma(const short* __restrict__ qk,
                                                 const short* __restrict__ vtg,
                                                 short* __restrict__ ctx,
                                                 float* __restrict__ opart,
                                                 float* __restrict__ pspart) {
    __shared__ short Kl[2][64*64];     // 16 KB: XOR-swizzled, double-buffered
    __shared__ short Vl[2][64*64];     // 16 KB: V^T [d][key], swizzled, dbuf
    __shared__ short Pl[4][16*64];     //  8 KB: granule-swizzled P bounce
    int t = threadIdx.x;
    int lane = t & 63, w = t >> 6;
    int l = lane & 15, quad = lane >> 4;
    int bh = blockIdx.x;               // 0..31 (XCD = bh%8)
    int y  = blockIdx.y;               // 0..47
    int qt, kc0, kc1, part; bool split;
    if (y < 16) { qt = y; kc0 = 0; kc1 = qt + 1; part = 0; split = false; }
    else {
        int z = y - 16;
        qt = 16 + (z >> 1); part = z & 1;
        int n = qt + 1, half = (n + 1) >> 1;
        kc0 = part ? half : 0; kc1 = part ? n : half; split = true;
    }
    int b = bh >> 4, h = bh & 15;
    size_t rbase = (size_t)b * Tm;
    const short* qp0 = qk + rbase * QKS + h*HDm;
    const short* kp0 = qp0 + Dm;
    const short* vh  = vtg + ((size_t)bh * HDm) * Tm;
    int qtbase = qt * 64;

    // Q fragments (B-operand): qf[s] = Q[q=l][dim s*32 + quad*8 + j]
    sh8 qf0, qf1;
    {
        const short* qp = qp0 + (size_t)(qtbase + w*16 + l) * QKS + quad*8;
        qf0 = *(const sh8*)qp;
        qf1 = *(const sh8*)(qp + 32);
    }
    f32x4 O[4] = {{0,0,0,0},{0,0,0,0},{0,0,0,0},{0,0,0,0}};
    float ps[4] = {0.f, 0.f, 0.f, 0.f};

    // ---- hoisted staging addresses (advance by constants per chunk) ----
    int offA = t*16, offB = 4096 + t*16;
    int rowA = offA >> 7, rowB = offB >> 7;
    int swA = ((offA >> 4) & 7) ^ (rowA & 7);
    int swB = ((offB >> 4) & 7) ^ (rowB & 7);
    const short* gkA = kp0 + (size_t)(kc0*64 + rowA) * QKS + swA*8;
    const short* gkB = kp0 + (size_t)(kc0*64 + rowB) * QKS + swB*8;
    const short* gvA = vh + (size_t)rowA * Tm + kc0*64 + swA*8;
    const short* gvB = vh + (size_t)rowB * Tm + kc0*64 + swB*8;

#define STAGE(KD, VD) do { \
    __builtin_amdgcn_global_load_lds(AS1(gkA), AS3((char*)(KD) + offA), 16, 0, 0); \
    __builtin_amdgcn_global_load_lds(AS1(gkB), AS3((char*)(KD) + offB), 16, 0, 0); \
    __builtin_amdgcn_global_load_lds(AS1(gvA), AS3((char*)(VD) + offA), 16, 0, 0); \
    __builtin_amdgcn_global_load_lds(AS1(gvB), AS3((char*)(VD) + offB), 16, 0, 0); \
    gkA += 64*QKS; gkB += 64*QKS; gvA += 64; gvB += 64; } while (0)

    STAGE(Kl[0], Vl[0]);
    __syncthreads();

    int swl = l & 7;                   // Pl granule swizzle key
    int cur = 0;
    for (int kc = kc0; kc < kc1; kc++) {
        int kbase = kc * 64;
        if (kc + 1 < kc1) {
            if (cur) STAGE(Kl[0], Vl[0]); else STAGE(Kl[1], Vl[1]);
        }

        // ---- S^T = K Q^T : S[kt] row=key(quad*4+r), col=q(l) ----
        f32x4 S[4];
        #pragma unroll
        for (int kt = 0; kt < 4; kt++) {
            const f32x4 z = {0.f,0.f,0.f,0.f};
            int key = kt*16 + l;
            const char* kb = (const char*)Kl[cur] + key*128;
            int sw = key & 7;
            sh8 k0 = *(const sh8*)(kb + ((quad ^ sw) * 16));
            sh8 k1 = *(const sh8*)(kb + (((4 + quad) ^ sw) * 16));
            f32x4 s = __builtin_amdgcn_mfma_f32_16x16x32_bf16(k0, qf0, z, 0, 0, 0);
            s = __builtin_amdgcn_mfma_f32_16x16x32_bf16(k1, qf1, s, 0, 0, 0);
            S[kt] = s;
        }
        // ---- p = exp(s) (wq pre-scaled), mask, accumulate l, pack bf16 ----
        bool needmask = (kbase + 63 > qtbase + w*16);
        int qrow = qtbase + w*16 + l;
        #pragma unroll
        for (int kt = 0; kt < 4; kt++) {
            float p[4];
            if (needmask) {
                #pragma unroll
                for (int r = 0; r < 4; r++) {
                    int key = kbase + kt*16 + quad*4 + r;
                    p[r] = (key > qrow) ? 0.f : __expf(S[kt][r]);
                }
            } else {
                #pragma unroll
                for (int r = 0; r < 4; r++)
                    p[r] = __expf(S[kt][r]);
            }
            ps[kt] += (p[0] + p[1]) + (p[2] + p[3]);
            __hip_bfloat162 pa = __float22bfloat162_rn({p[0], p[1]});
            __hip_bfloat162 pb = __float22bfloat162_rn({p[2], p[3]});
            union { __hip_bfloat162 hh[2]; short4 s4; } u;
            u.hh[0] = pa; u.hh[1] = pb;
            int g = (kt*2 + (quad >> 1)) ^ swl;
            *(short4*)&Pl[w][l*64 + g*8 + (quad & 1)*4] = u.s4;
        }
        // ---- P A-frags (granule-swizzled read) ----
        sh8 p0 = *(const sh8*)&Pl[w][l*64 + ((quad ^ swl) * 8)];
        sh8 p1 = *(const sh8*)&Pl[w][l*64 + (((4 + quad) ^ swl) * 8)];
        // ---- O += P V (C: row=q quad*4+r, col=dim l) ----
        #pragma unroll
        for (int dt = 0; dt < 4; dt++) {
            int d = dt*16 + l;
            const char* vb = (const char*)Vl[cur] + d*128;
            int sw = d & 7;
            sh8 v0 = *(const sh8*)(vb + ((quad ^ sw) * 16));
            sh8 v1 = *(const sh8*)(vb + (((4 + quad) ^ sw) * 16));
            O[dt] = __builtin_amdgcn_mfma_f32_16x16x32_bf16(p0, v0, O[dt], 0, 0, 0);
            O[dt] = __builtin_amdgcn_mfma_f32_16x16x32_bf16(p1, v1, O[dt], 0, 0, 0);
        }
        __syncthreads();   // drains prefetch gload_lds (issued pre-compute)
        cur ^= 1;
    }
#undef STAGE

    // ---- epilogue ----
    float psum = (ps[0] + ps[1]) + (ps[2] + ps[3]);
    psum += __shfl_xor(psum, 16);
    psum += __shfl_xor(psum, 32);      // all lanes: row-l total (this part)
    if (!split) {
        #pragma unroll
        for (int r = 0; r < 4; r++) {
            int src = (lane & 48) | (((lane >> 4) << 2) + r);
            float inv = 1.0f / __shfl(psum, src);
            int row = qtbase + w*16 + quad*4 + r;
            #pragma unroll
            for (int dt = 0; dt < 4; dt++)
                ctx[(rbase + row) * Dm + h*HDm + dt*16 + l] = f2bs(O[dt][r] * inv);
        }
    } else {
        int tile = (bh*16 + (qt - 16)) * 2 + part;
        float* ob = opart + (size_t)tile * 4096;
        #pragma unroll
        for (int r = 0; r < 4; r++) {
            int row = w*16 + quad*4 + r;
            #pragma unroll
            for (int dt = 0; dt < 4; dt++)
                ob[row*64 + dt*16 + l] = O[dt][r];
        }
        if (quad == 0) pspart[tile*64 + w*16 + l] = psum;
    }
}

// ---------------- combine: sum split-K partials, normalize, bf16 out ----
__global__ __launch_bounds__(256) void attn_combine(const float* __restrict__ opart,
                                                    const float* __restrict__ pspart,
                                                    short* __restrict__ ctx) {
    int bh = blockIdx.x;               // 0..31
    int q16 = blockIdx.y;              // 0..15 -> qt = 16+q16
    int b = bh >> 4, h = bh & 15;
    int t = threadIdx.x;
    int row = t >> 2;                  // 0..63
    int d0 = (t & 3) * 16;
    int tile0 = (bh*16 + q16) * 2;
    const float* o0 = opart + (size_t)tile0 * 4096 + row*64 + d0;
    const float* o1 = o0 + 4096;
    float psv = pspart[tile0*64 + row] + pspart[(tile0+1)*64 + row];
    float inv = 1.0f / psv;
    short* cp = ctx + ((size_t)(b*Tm + (16+q16)*64 + row)) * Dm + h*HDm + d0;
    #pragma unroll
    for (int j = 0; j < 16; j += 4) {
        float4 a = *(const float4*)(o0 + j);
        float4 c = *(const float4*)(o1 + j);
        short4 o;
        o.x = f2bs((a.x + c.x) * inv);
        o.y = f2bs((a.y + c.y) * inv);
        o.z = f2bs((a.z + c.z) * inv);
        o.w = f2bs((a.w + c.w) * inv);
        *(short4*)(cp + j) = o;
    }
}

// ---------------- launch ----------------
extern "C" void kernel_launch(void* const* d_in, const int* in_sizes, int n_in,
                              void* d_out, int out_size, void* d_ws, size_t ws_size,
                              hipStream_t stream) {
    const float* x   = (const float*)d_in[0];
    const float* wq  = (const float*)d_in[1];
    const float* wk  = (const float*)d_in[2];
    const float* wv  = (const float*)d_in[3];
    const float* wo  = (const float*)d_in[4];
    const float* bo  = (const float*)d_in[5];
    const float* ln1 = (const float*)d_in[6];
    const float* ln2 = (const float*)d_in[7];
    float* out = (float*)d_out;

    short* lnb  = (short*)d_ws;                      // 4096*1024 = 4M sh
    short* ctxb = lnb  + (size_t)Rm*Dm;              // 4M sh
    short* qk   = ctxb + (size_t)Rm*Dm;              // 8M sh
    short* vtg  = qk   + (size_t)Rm*QKS;             // 4M sh
    short* wqkv = vtg  + (size_t)Bm*Hm*HDm*Tm;       // 3M sh
    short* wob  = wqkv + (size_t)3*Dm*Dm;            // 1M sh
    float* opart  = (float*)(wob + (size_t)Dm*Dm);   // 32*16*2*4096 f = 16 MB
    float* pspart = opart + (size_t)32*16*2*4096;    // 64K f

    dim3 qgrid(3072/128, Rm/128);  // (24, 32)
    dim3 pgrid(Dm/64,    Rm/128);  // (16, 32)
    dim3 agrid(32, 48);            // (bh, y): y<16 direct, y>=16 split-K
    dim3 cgrid(32, 16);            // combine: (bh, qt-16)

    convert_w<<<4096, 256, 0, stream>>>(wq, wk, wv, wo, wqkv, wob);

    // ---- Block 1 ----
    ln_kernel<<<Rm, 256, 0, stream>>>(x, ln1, lnb);
    gemm_mfma<128, 1><<<qgrid, 256, 0, stream>>>(lnb, wqkv, nullptr, nullptr, qk, vtg, Rm, 3072, Dm);
    attn_mfma<<<agrid, 256, 0, stream>>>(qk, vtg, ctxb, opart, pspart);
    attn_combine<<<cgrid, 256, 0, stream>>>(opart, pspart, ctxb);
    gemm_mfma<64, 0><<<pgrid, 256, 0, stream>>>(ctxb, wob, bo, x, out, nullptr, Rm, Dm, Dm);

    // ---- Block 2 (same weights, ln2) ----
    ln_kernel<<<Rm, 256, 0, stream>>>(out, ln2, lnb);
    gemm_mfma<128, 1><<<qgrid, 256, 0, stream>>>(lnb, wqkv, nullptr, nullptr, qk, vtg, Rm, 3072, Dm);
    attn_mfma<<<agrid, 256, 0, stream>>>(qk, vtg, ctxb, opart, pspart);
    attn_combine<<<cgrid, 256, 0, stream>>>(opart, pspart, ctxb);
    gemm_mfma<64, 0><<<pgrid, 256, 0, stream>>>(ctxb, wob, bo, out, out, nullptr, Rm, Dm, Dm);
}